// Round 6
// baseline (1397.567 us; speedup 1.0000x reference)
//
#include <hip/hip_runtime.h>

// Problem constants (B,S,H,A) = (4,4096,1024,1024)
constexpr int Bb = 4;
constexpr int Ss = 4096;
constexpr int Hh = 1024;
constexpr int Aa = 1024;
constexpr int NROWS = Bb * Ss;     // 16384
constexpr int CS = 128;            // cumsum chunk rows
constexpr int NCHUNK = Ss / CS;    // 32

// ---------------------------------------------------------------------------
// Fused QKV SGEMM: Y[n,a] = sum_h X[n,h] * W[a,h]   (both row-major, K-contig)
// 128x128 tile, BK=16, 8x8 microtile per thread, 256 threads.
// blockIdx.z selects (Wq->Q, Wk->Kb, Wv->Vb).
// ---------------------------------------------------------------------------
__global__ __launch_bounds__(256) void qkv_gemm(
    const float* __restrict__ X,
    const float* __restrict__ Wq, const float* __restrict__ Wk, const float* __restrict__ Wv,
    float* __restrict__ Q, float* __restrict__ Kb, float* __restrict__ Vb)
{
    const float* W = (blockIdx.z == 0) ? Wq : (blockIdx.z == 1 ? Wk : Wv);
    float*       Y = (blockIdx.z == 0) ? Q  : (blockIdx.z == 1 ? Kb : Vb);

    __shared__ float Xs[16][132];   // [BK][BM+4] transposed store, pad kills conflicts
    __shared__ float Ws[16][132];

    const int t  = threadIdx.x;
    const int tx = t & 15;          // 16 cols of microtiles
    const int ty = t >> 4;          // 16 rows of microtiles
    const int row0 = blockIdx.x * 128;
    const int col0 = blockIdx.y * 128;

    float acc[8][8] = {};

    for (int k0 = 0; k0 < Hh; k0 += 16) {
        #pragma unroll
        for (int i = 0; i < 2; ++i) {
            const int f  = t + i * 256;      // 512 float4s per tile
            const int r  = f >> 2;           // tile row 0..127
            const int cg = f & 3;            // which float4 within the 16-wide K slab
            const float4 xv = *reinterpret_cast<const float4*>(X + (size_t)(row0 + r) * Hh + k0 + cg * 4);
            const float4 wv = *reinterpret_cast<const float4*>(W + (size_t)(col0 + r) * Hh + k0 + cg * 4);
            Xs[cg * 4 + 0][r] = xv.x; Xs[cg * 4 + 1][r] = xv.y;
            Xs[cg * 4 + 2][r] = xv.z; Xs[cg * 4 + 3][r] = xv.w;
            Ws[cg * 4 + 0][r] = wv.x; Ws[cg * 4 + 1][r] = wv.y;
            Ws[cg * 4 + 2][r] = wv.z; Ws[cg * 4 + 3][r] = wv.w;
        }
        __syncthreads();

        #pragma unroll
        for (int kk = 0; kk < 16; ++kk) {
            float a[8], b[8];
            *reinterpret_cast<float4*>(&a[0]) = *reinterpret_cast<const float4*>(&Xs[kk][ty * 8]);
            *reinterpret_cast<float4*>(&a[4]) = *reinterpret_cast<const float4*>(&Xs[kk][ty * 8 + 4]);
            *reinterpret_cast<float4*>(&b[0]) = *reinterpret_cast<const float4*>(&Ws[kk][tx * 8]);
            *reinterpret_cast<float4*>(&b[4]) = *reinterpret_cast<const float4*>(&Ws[kk][tx * 8 + 4]);
            #pragma unroll
            for (int i = 0; i < 8; ++i)
                #pragma unroll
                for (int j = 0; j < 8; ++j)
                    acc[i][j] = fmaf(a[i], b[j], acc[i][j]);
        }
        __syncthreads();
    }

    #pragma unroll
    for (int i = 0; i < 8; ++i) {
        float* dst = Y + (size_t)(row0 + ty * 8 + i) * Aa + col0 + tx * 8;
        *reinterpret_cast<float4*>(dst)     = make_float4(acc[i][0], acc[i][1], acc[i][2], acc[i][3]);
        *reinterpret_cast<float4*>(dst + 4) = make_float4(acc[i][4], acc[i][5], acc[i][6], acc[i][7]);
    }
}

// kv = k * v elementwise (in place over Vb)
__global__ __launch_bounds__(256) void kv_mul(const float* __restrict__ Kb, float* __restrict__ Vb)
{
    const size_t n4 = (size_t)NROWS * Aa / 4;
    for (size_t i = (size_t)blockIdx.x * blockDim.x + threadIdx.x; i < n4;
         i += (size_t)gridDim.x * blockDim.x) {
        const float4 k = reinterpret_cast<const float4*>(Kb)[i];
        const float4 v = reinterpret_cast<const float4*>(Vb)[i];
        reinterpret_cast<float4*>(Vb)[i] = make_float4(k.x * v.x, k.y * v.y, k.z * v.z, k.w * v.w);
    }
}

// Phase A: per-chunk column sums. grid = (B*NCHUNK, A/256, 2)
__global__ __launch_bounds__(256) void chunk_sum(
    const float* __restrict__ Kb, const float* __restrict__ Vb, float* __restrict__ part)
{
    const int z = blockIdx.z;                   // 0 -> K, 1 -> KV
    const int b = blockIdx.x / NCHUNK;
    const int c = blockIdx.x % NCHUNK;
    const int a = blockIdx.y * 256 + threadIdx.x;
    const float* src = z ? Vb : Kb;
    const size_t base = ((size_t)b * Ss + (size_t)c * CS) * Aa + a;
    float s = 0.f;
    for (int r = 0; r < CS; ++r) s += src[base + (size_t)r * Aa];
    part[(((size_t)z * Bb + b) * NCHUNK + c) * Aa + a] = s;
}

// Phase B: exclusive scan of the chunk sums. grid = (B, A/256, 2)
__global__ __launch_bounds__(256) void chunk_scan(float* __restrict__ part)
{
    const int z = blockIdx.z;
    const int b = blockIdx.x;
    const int a = blockIdx.y * 256 + threadIdx.x;
    float run = 0.f;
    for (int c = 0; c < NCHUNK; ++c) {
        const size_t i = (((size_t)z * Bb + b) * NCHUNK + c) * Aa + a;
        const float v = part[i];
        part[i] = run;
        run += v;
    }
}

// Phase C: in-place cumsum within each chunk, seeded by the scanned offset.
__global__ __launch_bounds__(256) void chunk_cumsum(
    float* __restrict__ Kb, float* __restrict__ Vb, const float* __restrict__ part)
{
    const int z = blockIdx.z;
    const int b = blockIdx.x / NCHUNK;
    const int c = blockIdx.x % NCHUNK;
    const int a = blockIdx.y * 256 + threadIdx.x;
    float* buf = z ? Vb : Kb;
    float run = part[(((size_t)z * Bb + b) * NCHUNK + c) * Aa + a];
    const size_t base = ((size_t)b * Ss + (size_t)c * CS) * Aa + a;
    for (int r = 0; r < CS; ++r) {
        const size_t i = base + (size_t)r * Aa;
        run += buf[i];
        buf[i] = run;
    }
}

// wo row-sums: one block per h.
__global__ __launch_bounds__(256) void wo_rowsum_k(const float* __restrict__ wo, float* __restrict__ rs)
{
    const int h = blockIdx.x;
    float s = 0.f;
    for (int j = threadIdx.x; j < Aa; j += 256) s += wo[(size_t)h * Aa + j];
    #pragma unroll
    for (int off = 32; off; off >>= 1) s += __shfl_down(s, off);
    __shared__ float sm[4];
    const int lane = threadIdx.x & 63, wid = threadIdx.x >> 6;
    if (lane == 0) sm[wid] = s;
    __syncthreads();
    if (threadIdx.x == 0) rs[h] = sm[0] + sm[1] + sm[2] + sm[3];
}

// Final: per-row num/den dot (q lives in d_out), then out[row,h] = score*rs[h].
__global__ __launch_bounds__(256) void score_out(
    const float* __restrict__ Kc, const float* __restrict__ KVc,
    const float* __restrict__ rs, float* __restrict__ out)
{
    const int row = blockIdx.x;
    const size_t base = (size_t)row * Aa;
    float num = 0.f, den = 0.f;
    #pragma unroll
    for (int j = 0; j < 4; ++j) {
        const int a = threadIdx.x + j * 256;
        const float qa = out[base + a];          // q row staged in d_out
        num = fmaf(qa, KVc[base + a], num);
        den = fmaf(qa, Kc[base + a], den);
    }
    #pragma unroll
    for (int off = 32; off; off >>= 1) {
        num += __shfl_down(num, off);
        den += __shfl_down(den, off);
    }
    __shared__ float sn[4], sd[4];
    __shared__ float sc;
    const int lane = threadIdx.x & 63, wid = threadIdx.x >> 6;
    if (lane == 0) { sn[wid] = num; sd[wid] = den; }
    __syncthreads();
    if (threadIdx.x == 0) {
        const float n = sn[0] + sn[1] + sn[2] + sn[3];
        const float d = sd[0] + sd[1] + sd[2] + sd[3] + 1e-6f;
        sc = n / d;
    }
    __syncthreads();                              // also orders q reads before writes
    const float s = sc;
    #pragma unroll
    for (int j = 0; j < 4; ++j) {
        const int a = threadIdx.x + j * 256;
        out[base + a] = s * rs[a];
    }
}

extern "C" void kernel_launch(void* const* d_in, const int* in_sizes, int n_in,
                              void* d_out, int out_size, void* d_ws, size_t ws_size,
                              hipStream_t stream)
{
    const float* hidden = (const float*)d_in[0];
    const float* wq = (const float*)d_in[1];
    const float* wk = (const float*)d_in[2];
    const float* wv = (const float*)d_in[3];
    const float* wo = (const float*)d_in[4];
    float* out = (float*)d_out;

    float* Kb   = (float*)d_ws;                          // 16M floats
    float* Vb   = Kb + (size_t)NROWS * Aa;               // 16M floats
    float* part = Vb + (size_t)NROWS * Aa;               // 2*B*NCHUNK*A = 256K floats
    float* rs   = part + (size_t)2 * Bb * NCHUNK * Aa;   // 1024 floats
    // total ws use: ~129.1 MB

    qkv_gemm<<<dim3(NROWS / 128, Aa / 128, 3), 256, 0, stream>>>(hidden, wq, wk, wv, out, Kb, Vb);
    kv_mul<<<2048, 256, 0, stream>>>(Kb, Vb);
    chunk_sum<<<dim3(Bb * NCHUNK, Aa / 256, 2), 256, 0, stream>>>(Kb, Vb, part);
    chunk_scan<<<dim3(Bb, Aa / 256, 2), 256, 0, stream>>>(part);
    chunk_cumsum<<<dim3(Bb * NCHUNK, Aa / 256, 2), 256, 0, stream>>>(Kb, Vb, part);
    wo_rowsum_k<<<Hh, 256, 0, stream>>>(wo, rs);
    score_out<<<NROWS, 256, 0, stream>>>(Kb, Vb, rs, out);
}

// Round 7
// 750.013 us; speedup vs baseline: 1.8634x; 1.8634x over previous
//
#include <hip/hip_runtime.h>
#include <hip/hip_bf16.h>

// Problem constants (B,S,H,A) = (4,4096,1024,1024)
constexpr int Bb = 4;
constexpr int Ss = 4096;
constexpr int Hh = 1024;
constexpr int Aa = 1024;
constexpr int NROWS = Bb * Ss;     // 16384
constexpr int CS = 128;            // cumsum chunk rows
constexpr int NCHUNK = Ss / CS;    // 32

typedef __attribute__((ext_vector_type(8))) short short8;
typedef __attribute__((ext_vector_type(16))) float f32x16;

// ---------------------------------------------------------------------------
// split_pack: fp32 [R][1024] -> 3-way bf16 split, fragment-packed for
// mfma_f32_32x32x16_bf16. Pack layout (ushort index):
//   (((rt*64 + kt)*3 + s)*4 + ms)*512 + lane*8 + e
// where rt = row/128, kt = k/16, ms = (row%128)/32, and fragment lane mapping
//   lane = (row%32) | (((k%16)/8)<<5), e = k%8
// i.e. each 512-ushort chunk is exactly one wave's A/B fragment (lane-contig
// 16B -> conflict-free ds_read_b128, and global_load_lds stages it linearly).
// ---------------------------------------------------------------------------
__global__ __launch_bounds__(256) void split_pack(
    const float* __restrict__ src, unsigned short* __restrict__ dst, int ntiles)
{
    const int gid  = blockIdx.x * 256 + threadIdx.x;
    const int lane = gid & 63;
    const int ms   = (gid >> 6) & 3;
    const int kt   = (gid >> 8) & 63;
    const int rt   = gid >> 14;
    if (rt >= ntiles) return;
    const int row = rt * 128 + ms * 32 + (lane & 31);
    const int k0  = kt * 16 + (lane >> 5) * 8;
    const float* p = src + (size_t)row * 1024 + k0;
    const float4 xa = *reinterpret_cast<const float4*>(p);
    const float4 xb = *reinterpret_cast<const float4*>(p + 4);
    const float xs[8] = {xa.x, xa.y, xa.z, xa.w, xb.x, xb.y, xb.z, xb.w};
    short8 v1, v2, v3;
    #pragma unroll
    for (int e = 0; e < 8; ++e) {
        float x = xs[e];
        __hip_bfloat16 h1 = __float2bfloat16(x);
        float r1 = x - __bfloat162float(h1);
        __hip_bfloat16 h2 = __float2bfloat16(r1);
        float r2 = r1 - __bfloat162float(h2);
        __hip_bfloat16 h3 = __float2bfloat16(r2);
        unsigned short u1, u2, u3;
        __builtin_memcpy(&u1, &h1, 2);
        __builtin_memcpy(&u2, &h2, 2);
        __builtin_memcpy(&u3, &h3, 2);
        v1[e] = (short)u1; v2[e] = (short)u2; v3[e] = (short)u3;
    }
    const size_t base = (size_t)(rt * 64 + kt) * 6144 + (size_t)ms * 512 + (size_t)lane * 8;
    *reinterpret_cast<short8*>(dst + base)        = v1;   // s = 0
    *reinterpret_cast<short8*>(dst + base + 2048) = v2;   // s = 1
    *reinterpret_cast<short8*>(dst + base + 4096) = v3;   // s = 2
}

// ---------------------------------------------------------------------------
// Split-bf16 MFMA GEMM: Y[n,a] = sum_h X[n,h]*W[a,h] via 6 cross-products of
// the 3-way splits (truncation ~2^-26 rel, below fp32 eps).
// 128x128 block tile, BK=32, 4 waves (2x2), 64x64 per wave in 2x2 frags of
// 32x32x16. LDS 48KB single-buffered, staged with global_load_lds width 16.
// ---------------------------------------------------------------------------
__global__ __launch_bounds__(256) void qkv_gemm_split(
    const unsigned short* __restrict__ Xp, const unsigned short* __restrict__ Wp,
    float* __restrict__ Q, float* __restrict__ Kb, float* __restrict__ Vb)
{
    const int z = blockIdx.z;
    float* Y = (z == 0) ? Q : ((z == 1) ? Kb : Vb);
    const unsigned short* Wz = Wp + (size_t)z * 3145728;   // 8*64*6144 per matrix

    __shared__ __align__(16) unsigned short As[12288];   // [kh 2][s 3][ms 4][512]
    __shared__ __align__(16) unsigned short Bs[12288];

    const int tid = threadIdx.x, wid = tid >> 6, lane = tid & 63;
    const int rt = blockIdx.x, ct = blockIdx.y;
    const int wm = wid >> 1, wn = wid & 1;

    f32x16 acc[2][2];
    #pragma unroll
    for (int i = 0; i < 2; ++i)
        #pragma unroll
        for (int j = 0; j < 2; ++j)
            #pragma unroll
            for (int r = 0; r < 16; ++r) acc[i][j][r] = 0.f;

    const unsigned short* gA = Xp + (size_t)rt * 393216;   // rt*64*6144
    const unsigned short* gB = Wz + (size_t)ct * 393216;

    for (int t = 0; t < 32; ++t) {
        #pragma unroll
        for (int j = 0; j < 6; ++j) {
            __builtin_amdgcn_global_load_lds(
                (const __attribute__((address_space(1))) void*)(gA + (size_t)t * 12288 + j * 2048 + tid * 8),
                (__attribute__((address_space(3))) void*)(As + j * 2048 + wid * 512),
                16, 0, 0);
        }
        #pragma unroll
        for (int j = 0; j < 6; ++j) {
            __builtin_amdgcn_global_load_lds(
                (const __attribute__((address_space(1))) void*)(gB + (size_t)t * 12288 + j * 2048 + tid * 8),
                (__attribute__((address_space(3))) void*)(Bs + j * 2048 + wid * 512),
                16, 0, 0);
        }
        __syncthreads();   // compiler inserts vmcnt(0) before barrier

        #pragma unroll
        for (int kh = 0; kh < 2; ++kh) {
            short8 af[2][3], bq[2][3];
            #pragma unroll
            for (int mi = 0; mi < 2; ++mi)
                #pragma unroll
                for (int s = 0; s < 3; ++s)
                    af[mi][s] = *reinterpret_cast<const short8*>(
                        As + kh * 6144 + s * 2048 + (wm * 2 + mi) * 512 + lane * 8);
            #pragma unroll
            for (int ni = 0; ni < 2; ++ni)
                #pragma unroll
                for (int s = 0; s < 3; ++s)
                    bq[ni][s] = *reinterpret_cast<const short8*>(
                        Bs + kh * 6144 + s * 2048 + (wn * 2 + ni) * 512 + lane * 8);
            #pragma unroll
            for (int mi = 0; mi < 2; ++mi)
                #pragma unroll
                for (int ni = 0; ni < 2; ++ni) {
                    f32x16 a = acc[mi][ni];
                    // smallest-magnitude terms first
                    a = __builtin_amdgcn_mfma_f32_32x32x16_bf16(af[mi][0], bq[ni][2], a, 0, 0, 0);
                    a = __builtin_amdgcn_mfma_f32_32x32x16_bf16(af[mi][1], bq[ni][1], a, 0, 0, 0);
                    a = __builtin_amdgcn_mfma_f32_32x32x16_bf16(af[mi][2], bq[ni][0], a, 0, 0, 0);
                    a = __builtin_amdgcn_mfma_f32_32x32x16_bf16(af[mi][0], bq[ni][1], a, 0, 0, 0);
                    a = __builtin_amdgcn_mfma_f32_32x32x16_bf16(af[mi][1], bq[ni][0], a, 0, 0, 0);
                    a = __builtin_amdgcn_mfma_f32_32x32x16_bf16(af[mi][0], bq[ni][0], a, 0, 0, 0);
                    acc[mi][ni] = a;
                }
        }
        __syncthreads();   // all reads done before next stage overwrites
    }

    // Epilogue: C/D layout col=lane&31, row=(r&3)+8*(r>>2)+4*(lane>>5)
    const int r0 = rt * 128 + wm * 64;
    const int c0 = ct * 128 + wn * 64 + (lane & 31);
    const int rl = 4 * (lane >> 5);
    #pragma unroll
    for (int mi = 0; mi < 2; ++mi)
        #pragma unroll
        for (int ni = 0; ni < 2; ++ni)
            #pragma unroll
            for (int r = 0; r < 16; ++r) {
                const int row = r0 + mi * 32 + (r & 3) + 8 * (r >> 2) + rl;
                Y[(size_t)row * 1024 + c0 + ni * 32] = acc[mi][ni][r];
            }
}

// ---------------------------------------------------------------------------
// Fallback fp32 SGEMM (used only if ws_size too small for the split path).
// ---------------------------------------------------------------------------
__global__ __launch_bounds__(256) void qkv_gemm(
    const float* __restrict__ X,
    const float* __restrict__ Wq, const float* __restrict__ Wk, const float* __restrict__ Wv,
    float* __restrict__ Q, float* __restrict__ Kb, float* __restrict__ Vb)
{
    const float* W = (blockIdx.z == 0) ? Wq : (blockIdx.z == 1 ? Wk : Wv);
    float*       Y = (blockIdx.z == 0) ? Q  : (blockIdx.z == 1 ? Kb : Vb);

    __shared__ float Xs[16][132];
    __shared__ float Ws[16][132];

    const int t  = threadIdx.x;
    const int tx = t & 15;
    const int ty = t >> 4;
    const int row0 = blockIdx.x * 128;
    const int col0 = blockIdx.y * 128;

    float acc[8][8] = {};

    for (int k0 = 0; k0 < Hh; k0 += 16) {
        #pragma unroll
        for (int i = 0; i < 2; ++i) {
            const int f  = t + i * 256;
            const int r  = f >> 2;
            const int cg = f & 3;
            const float4 xv = *reinterpret_cast<const float4*>(X + (size_t)(row0 + r) * Hh + k0 + cg * 4);
            const float4 wv = *reinterpret_cast<const float4*>(W + (size_t)(col0 + r) * Hh + k0 + cg * 4);
            Xs[cg * 4 + 0][r] = xv.x; Xs[cg * 4 + 1][r] = xv.y;
            Xs[cg * 4 + 2][r] = xv.z; Xs[cg * 4 + 3][r] = xv.w;
            Ws[cg * 4 + 0][r] = wv.x; Ws[cg * 4 + 1][r] = wv.y;
            Ws[cg * 4 + 2][r] = wv.z; Ws[cg * 4 + 3][r] = wv.w;
        }
        __syncthreads();

        #pragma unroll
        for (int kk = 0; kk < 16; ++kk) {
            float a[8], b[8];
            *reinterpret_cast<float4*>(&a[0]) = *reinterpret_cast<const float4*>(&Xs[kk][ty * 8]);
            *reinterpret_cast<float4*>(&a[4]) = *reinterpret_cast<const float4*>(&Xs[kk][ty * 8 + 4]);
            *reinterpret_cast<float4*>(&b[0]) = *reinterpret_cast<const float4*>(&Ws[kk][tx * 8]);
            *reinterpret_cast<float4*>(&b[4]) = *reinterpret_cast<const float4*>(&Ws[kk][tx * 8 + 4]);
            #pragma unroll
            for (int i = 0; i < 8; ++i)
                #pragma unroll
                for (int j = 0; j < 8; ++j)
                    acc[i][j] = fmaf(a[i], b[j], acc[i][j]);
        }
        __syncthreads();
    }

    #pragma unroll
    for (int i = 0; i < 8; ++i) {
        float* dst = Y + (size_t)(row0 + ty * 8 + i) * Aa + col0 + tx * 8;
        *reinterpret_cast<float4*>(dst)     = make_float4(acc[i][0], acc[i][1], acc[i][2], acc[i][3]);
        *reinterpret_cast<float4*>(dst + 4) = make_float4(acc[i][4], acc[i][5], acc[i][6], acc[i][7]);
    }
}

// kv = k * v elementwise (in place over Vb)
__global__ __launch_bounds__(256) void kv_mul(const float* __restrict__ Kb, float* __restrict__ Vb)
{
    const size_t n4 = (size_t)NROWS * Aa / 4;
    for (size_t i = (size_t)blockIdx.x * blockDim.x + threadIdx.x; i < n4;
         i += (size_t)gridDim.x * blockDim.x) {
        const float4 k = reinterpret_cast<const float4*>(Kb)[i];
        const float4 v = reinterpret_cast<const float4*>(Vb)[i];
        reinterpret_cast<float4*>(Vb)[i] = make_float4(k.x * v.x, k.y * v.y, k.z * v.z, k.w * v.w);
    }
}

// Phase A: per-chunk column sums. grid = (B*NCHUNK, A/256, 2)
__global__ __launch_bounds__(256) void chunk_sum(
    const float* __restrict__ Kb, const float* __restrict__ Vb, float* __restrict__ part)
{
    const int z = blockIdx.z;
    const int b = blockIdx.x / NCHUNK;
    const int c = blockIdx.x % NCHUNK;
    const int a = blockIdx.y * 256 + threadIdx.x;
    const float* src = z ? Vb : Kb;
    const size_t base = ((size_t)b * Ss + (size_t)c * CS) * Aa + a;
    float s = 0.f;
    for (int r = 0; r < CS; ++r) s += src[base + (size_t)r * Aa];
    part[(((size_t)z * Bb + b) * NCHUNK + c) * Aa + a] = s;
}

// Phase B: exclusive scan of the chunk sums. grid = (B, A/256, 2)
__global__ __launch_bounds__(256) void chunk_scan(float* __restrict__ part)
{
    const int z = blockIdx.z;
    const int b = blockIdx.x;
    const int a = blockIdx.y * 256 + threadIdx.x;
    float run = 0.f;
    for (int c = 0; c < NCHUNK; ++c) {
        const size_t i = (((size_t)z * Bb + b) * NCHUNK + c) * Aa + a;
        const float v = part[i];
        part[i] = run;
        run += v;
    }
}

// Phase C: in-place cumsum within each chunk, seeded by the scanned offset.
__global__ __launch_bounds__(256) void chunk_cumsum(
    float* __restrict__ Kb, float* __restrict__ Vb, const float* __restrict__ part)
{
    const int z = blockIdx.z;
    const int b = blockIdx.x / NCHUNK;
    const int c = blockIdx.x % NCHUNK;
    const int a = blockIdx.y * 256 + threadIdx.x;
    float* buf = z ? Vb : Kb;
    float run = part[(((size_t)z * Bb + b) * NCHUNK + c) * Aa + a];
    const size_t base = ((size_t)b * Ss + (size_t)c * CS) * Aa + a;
    for (int r = 0; r < CS; ++r) {
        const size_t i = base + (size_t)r * Aa;
        run += buf[i];
        buf[i] = run;
    }
}

// wo row-sums: one block per h.
__global__ __launch_bounds__(256) void wo_rowsum_k(const float* __restrict__ wo, float* __restrict__ rs)
{
    const int h = blockIdx.x;
    float s = 0.f;
    for (int j = threadIdx.x; j < Aa; j += 256) s += wo[(size_t)h * Aa + j];
    #pragma unroll
    for (int off = 32; off; off >>= 1) s += __shfl_down(s, off);
    __shared__ float sm[4];
    const int lane = threadIdx.x & 63, wid = threadIdx.x >> 6;
    if (lane == 0) sm[wid] = s;
    __syncthreads();
    if (threadIdx.x == 0) rs[h] = sm[0] + sm[1] + sm[2] + sm[3];
}

// Final: per-row num/den dot (q lives in d_out), then out[row,h] = score*rs[h].
__global__ __launch_bounds__(256) void score_out(
    const float* __restrict__ Kc, const float* __restrict__ KVc,
    const float* __restrict__ rs, float* __restrict__ out)
{
    const int row = blockIdx.x;
    const size_t base = (size_t)row * Aa;
    float num = 0.f, den = 0.f;
    #pragma unroll
    for (int j = 0; j < 4; ++j) {
        const int a = threadIdx.x + j * 256;
        const float qa = out[base + a];
        num = fmaf(qa, KVc[base + a], num);
        den = fmaf(qa, Kc[base + a], den);
    }
    #pragma unroll
    for (int off = 32; off; off >>= 1) {
        num += __shfl_down(num, off);
        den += __shfl_down(den, off);
    }
    __shared__ float sn[4], sd[4];
    __shared__ float sc;
    const int lane = threadIdx.x & 63, wid = threadIdx.x >> 6;
    if (lane == 0) { sn[wid] = num; sd[wid] = den; }
    __syncthreads();
    if (threadIdx.x == 0) {
        const float n = sn[0] + sn[1] + sn[2] + sn[3];
        const float d = sd[0] + sd[1] + sd[2] + sd[3] + 1e-6f;
        sc = n / d;
    }
    __syncthreads();
    const float s = sc;
    #pragma unroll
    for (int j = 0; j < 4; ++j) {
        const int a = threadIdx.x + j * 256;
        out[base + a] = s * rs[a];
    }
}

extern "C" void kernel_launch(void* const* d_in, const int* in_sizes, int n_in,
                              void* d_out, int out_size, void* d_ws, size_t ws_size,
                              hipStream_t stream)
{
    const float* hidden = (const float*)d_in[0];
    const float* wq = (const float*)d_in[1];
    const float* wk = (const float*)d_in[2];
    const float* wv = (const float*)d_in[3];
    const float* wo = (const float*)d_in[4];
    float* out = (float*)d_out;

    // workspace layout
    float* Kb   = (float*)d_ws;                          // 67,108,864 B
    float* Vb   = Kb + (size_t)NROWS * Aa;               // 67,108,864 B
    float* part = Vb + (size_t)NROWS * Aa;               // 1,048,576 B
    float* rs   = part + (size_t)2 * Bb * NCHUNK * Aa;   // 4,096 B
    unsigned short* Xp = (unsigned short*)(rs + 1024);   // 100,663,296 B
    unsigned short* Wp = Xp + (size_t)50331648;          // 18,874,368 B
    const size_t need_split = 254808064;                 // bytes

    if (ws_size >= need_split) {
        // 3-way bf16 split + pack (X: 128 row-tiles; each W: 8 row-tiles)
        split_pack<<<8192, 256, 0, stream>>>(hidden, Xp, 128);
        split_pack<<<512, 256, 0, stream>>>(wq, Wp,                       8);
        split_pack<<<512, 256, 0, stream>>>(wk, Wp + (size_t)3145728,     8);
        split_pack<<<512, 256, 0, stream>>>(wv, Wp + (size_t)2 * 3145728, 8);
        qkv_gemm_split<<<dim3(NROWS / 128, Aa / 128, 3), 256, 0, stream>>>(Xp, Wp, out, Kb, Vb);
    } else {
        qkv_gemm<<<dim3(NROWS / 128, Aa / 128, 3), 256, 0, stream>>>(hidden, wq, wk, wv, out, Kb, Vb);
    }

    kv_mul<<<2048, 256, 0, stream>>>(Kb, Vb);
    chunk_sum<<<dim3(Bb * NCHUNK, Aa / 256, 2), 256, 0, stream>>>(Kb, Vb, part);
    chunk_scan<<<dim3(Bb, Aa / 256, 2), 256, 0, stream>>>(part);
    chunk_cumsum<<<dim3(Bb * NCHUNK, Aa / 256, 2), 256, 0, stream>>>(Kb, Vb, part);
    wo_rowsum_k<<<Hh, 256, 0, stream>>>(wo, rs);
    score_out<<<NROWS, 256, 0, stream>>>(Kb, Vb, rs, out);
}